// Round 9
// baseline (470.762 us; speedup 1.0000x reference)
//
#include <hip/hip_runtime.h>
#include <math.h>

#define B_    64
#define KP1   16385                 // K+1
#define D_    128
#define NROW  500000
#define INV_T (1.0f / 0.07f)
#define MOM_  0.5f

#define BK_    (B_ * KP1)           // 1,048,640 items (=entries); %4 == 0
#define NE4B   (NROW * (D_ / 4))    // 16,000,000 float4 per bank
#define NBLK   2048
#define NTHR   (NBLK * 256)         // 524,288 threads
#define NGRP   (NBLK * 8)           // 16,384 32-lane groups
#define NQUADE (BK_ / 4)            // 262,160 entry quads
#define NSTEP  16                   // NQUADE / NGRP
#define REMG   (NQUADE - NSTEP * NGRP)  // 16 leftover quads
#define CPITER 31                   // ceil(NE4B / NTHR); iter 30 partial

#define CHUNKSZ 2048
#define NCHUNK  245                 // ceil(NROW / CHUNKSZ)
#define PADROWS (NCHUNK * CHUNKSZ)  // 501,760

// ---- d_ws layout (bytes) ----
#define WS_COUNTS   0                               // int[PADROWS]
#define WS_PARTIAL  (WS_COUNTS  + PADROWS * 4)      // int[PADROWS] (becomes cursor)
#define WS_BSUM     (WS_PARTIAL + PADROWS * 4)      // int[256]
#define WS_BSCAN    (WS_BSUM    + 256 * 4)          // int[256]
#define WS_ENTRIES  (WS_BSCAN   + 256 * 4)          // int2[BK_]  (r, u)

typedef float vfloat4 __attribute__((ext_vector_type(4)));

__device__ __forceinline__ float dot4(const float4 r, const float4 f) {
    return r.x * f.x + r.y * f.y + r.z * f.z + r.w * f.w;
}

// K1: histogram of row ids
__global__ __launch_bounds__(256)
void hist_kernel(const int* __restrict__ idx, int* __restrict__ counts) {
    for (unsigned u = blockIdx.x * 256u + threadIdx.x; u < (unsigned)BK_;
         u += gridDim.x * 256u)
        atomicAdd(&counts[idx[u]], 1);
}

// K2a: per-2048-chunk exclusive scan of counts -> partial; chunk totals -> bsum
__global__ __launch_bounds__(256)
void scan1_kernel(const int* __restrict__ counts, int* __restrict__ partial,
                  int* __restrict__ bsum) {
    __shared__ int tsum[256];
    const int tid  = threadIdx.x;
    const int base = blockIdx.x * CHUNKSZ + tid * 8;

    int c[8], pre[8], run = 0;
    #pragma unroll
    for (int i = 0; i < 8; ++i) c[i] = counts[base + i];
    #pragma unroll
    for (int i = 0; i < 8; ++i) { pre[i] = run; run += c[i]; }

    tsum[tid] = run;
    __syncthreads();
    for (int off = 1; off < 256; off <<= 1) {
        const int add = (tid >= off) ? tsum[tid - off] : 0;
        __syncthreads();
        tsum[tid] += add;
        __syncthreads();
    }
    const int toff = tsum[tid] - run;   // exclusive within chunk
    #pragma unroll
    for (int i = 0; i < 8; ++i) partial[base + i] = toff + pre[i];
    if (tid == 255) bsum[blockIdx.x] = tsum[255];
}

// K2b: exclusive scan of the 245 chunk totals
__global__ __launch_bounds__(256)
void scan2_kernel(const int* __restrict__ bsum, int* __restrict__ bscan) {
    __shared__ int tsum[256];
    const int tid = threadIdx.x;
    const int v = (tid < NCHUNK) ? bsum[tid] : 0;
    tsum[tid] = v;
    __syncthreads();
    for (int off = 1; off < 256; off <<= 1) {
        const int add = (tid >= off) ? tsum[tid - off] : 0;
        __syncthreads();
        tsum[tid] += add;
        __syncthreads();
    }
    bscan[tid] = tsum[tid] - v;         // exclusive
}

// K3: scatter (r, u) into row-sorted entry array; partial[] doubles as cursor
__global__ __launch_bounds__(256)
void scatter_kernel(const int* __restrict__ idx, int* __restrict__ cursor,
                    const int* __restrict__ bscan, int2* __restrict__ entries) {
    for (unsigned u = blockIdx.x * 256u + threadIdx.x; u < (unsigned)BK_;
         u += gridDim.x * 256u) {
        const int r = idx[u];
        const int pos = atomicAdd(&cursor[r], 1) + bscan[r >> 11];
        entries[pos] = make_int2(r, (int)u);
    }
}

__device__ __forceinline__ void copy_iter(const vfloat4* __restrict__ src,
                                          vfloat4* __restrict__ dst,
                                          int c, unsigned tid) {
    if (c < CPITER) {
        const size_t e = (size_t)c * NTHR + tid;
        if (e < (size_t)NE4B)
            __builtin_nontemporal_store(src[e], dst + e);
    }
}

// One quad of 4 row-sorted entries: each entry -> both dots + 2 stores.
__device__ __forceinline__ void entry_quad(
        unsigned q, int glane,
        const float* __restrict__ l, const float* __restrict__ ab,
        const float* __restrict__ mem_l, const float* __restrict__ mem_ab,
        const int2* __restrict__ entries, float* __restrict__ out) {
    const int4 w0 = ((const int4*)(entries + 4u * q))[0];  // r0,u0,r1,u1
    const int4 w1 = ((const int4*)(entries + 4u * q))[1];  // r2,u2,r3,u3
    const int r0 = w0.x, u0 = w0.y, r1 = w0.z, u1 = w0.w;
    const int r2 = w1.x, u2 = w1.y, r3 = w1.z, u3 = w1.w;

    const unsigned b0 = (unsigned)u0 / KP1, b1 = (unsigned)u1 / KP1;
    const unsigned b2 = (unsigned)u2 / KP1, b3 = (unsigned)u3 / KP1;

    // 8 cooperative row bursts (512B each); consecutive entries share rows -> cache hits
    const float4 a0 = ((const float4*)(mem_ab + (size_t)r0 * D_))[glane];
    const float4 m0 = ((const float4*)(mem_l  + (size_t)r0 * D_))[glane];
    const float4 a1 = ((const float4*)(mem_ab + (size_t)r1 * D_))[glane];
    const float4 m1 = ((const float4*)(mem_l  + (size_t)r1 * D_))[glane];
    const float4 a2 = ((const float4*)(mem_ab + (size_t)r2 * D_))[glane];
    const float4 m2 = ((const float4*)(mem_l  + (size_t)r2 * D_))[glane];
    const float4 a3 = ((const float4*)(mem_ab + (size_t)r3 * D_))[glane];
    const float4 m3 = ((const float4*)(mem_l  + (size_t)r3 * D_))[glane];

    // feature fragments (64KB hot set, L1/L2)
    const float4 fl0 = ((const float4*)(l  + (size_t)b0 * D_))[glane];
    const float4 fa0 = ((const float4*)(ab + (size_t)b0 * D_))[glane];
    const float4 fl1 = ((const float4*)(l  + (size_t)b1 * D_))[glane];
    const float4 fa1 = ((const float4*)(ab + (size_t)b1 * D_))[glane];
    const float4 fl2 = ((const float4*)(l  + (size_t)b2 * D_))[glane];
    const float4 fa2 = ((const float4*)(ab + (size_t)b2 * D_))[glane];
    const float4 fl3 = ((const float4*)(l  + (size_t)b3 * D_))[glane];
    const float4 fa3 = ((const float4*)(ab + (size_t)b3 * D_))[glane];

    float sl0 = dot4(a0, fl0), sa0 = dot4(m0, fa0);
    float sl1 = dot4(a1, fl1), sa1 = dot4(m1, fa1);
    float sl2 = dot4(a2, fl2), sa2 = dot4(m2, fa2);
    float sl3 = dot4(a3, fl3), sa3 = dot4(m3, fa3);

    #pragma unroll
    for (int m = 16; m >= 1; m >>= 1) {
        sl0 += __shfl_xor(sl0, m);  sa0 += __shfl_xor(sa0, m);
        sl1 += __shfl_xor(sl1, m);  sa1 += __shfl_xor(sa1, m);
        sl2 += __shfl_xor(sl2, m);  sa2 += __shfl_xor(sa2, m);
        sl3 += __shfl_xor(sl3, m);  sa3 += __shfl_xor(sa3, m);
    }
    if (glane == 0) {
        __builtin_nontemporal_store(sl0 * INV_T, out + u0);
        __builtin_nontemporal_store(sl1 * INV_T, out + u1);
        __builtin_nontemporal_store(sl2 * INV_T, out + u2);
        __builtin_nontemporal_store(sl3 * INV_T, out + u3);
    } else if (glane == 1) {
        __builtin_nontemporal_store(sa0 * INV_T, out + BK_ + u0);
        __builtin_nontemporal_store(sa1 * INV_T, out + BK_ + u1);
        __builtin_nontemporal_store(sa2 * INV_T, out + BK_ + u2);
        __builtin_nontemporal_store(sa3 * INV_T, out + BK_ + u3);
    }
}

// K4 main: streaming bank copy (front) + row-sorted entry scoring (band)
// marching together: copy covers 32.8k rows/step, gather band 31.3k rows/step.
__global__ __launch_bounds__(256)
void stream_kernel(const float* __restrict__ l,
                   const float* __restrict__ ab,
                   const float* __restrict__ mem_l,
                   const float* __restrict__ mem_ab,
                   const int2* __restrict__ entries,
                   float* __restrict__ out,          // scores [2*BK_]
                   float* __restrict__ out_mem_l,
                   float* __restrict__ out_mem_ab) {
    const unsigned tid   = blockIdx.x * 256u + threadIdx.x;
    const int      glane = threadIdx.x & 31;
    const unsigned g     = (blockIdx.x << 3) + (threadIdx.x >> 5);

    const vfloat4* srcL = (const vfloat4*)mem_l;
    const vfloat4* srcA = (const vfloat4*)mem_ab;
    vfloat4* dstL = (vfloat4*)out_mem_l;
    vfloat4* dstA = (vfloat4*)out_mem_ab;

    for (int j = 0; j < NSTEP; ++j) {
        copy_iter(srcL, dstL, 2 * j,     tid);
        copy_iter(srcA, dstA, 2 * j,     tid);
        copy_iter(srcL, dstL, 2 * j + 1, tid);
        copy_iter(srcA, dstA, 2 * j + 1, tid);
        entry_quad(g + (unsigned)j * NGRP, glane,
                   l, ab, mem_l, mem_ab, entries, out);
    }
    if (g < REMG)
        entry_quad((unsigned)NSTEP * NGRP + g, glane,
                   l, ab, mem_l, mem_ab, entries, out);
}

// K5: EMA + L2-normalize the B updated rows (after stream_kernel in order)
__global__ __launch_bounds__(128)
void ema_update_kernel(const float* __restrict__ l,
                       const float* __restrict__ ab,
                       const float* __restrict__ mem_l,
                       const float* __restrict__ mem_ab,
                       const int* __restrict__ y,
                       float* __restrict__ out_mem_l,
                       float* __restrict__ out_mem_ab) {
    const int b    = blockIdx.x;
    const int wave = threadIdx.x >> 6;
    const int lane = threadIdx.x & 63;
    const int yb   = y[b];

    const float* mem  = wave ? mem_ab     : mem_l;
    const float* feat = wave ? ab         : l;
    float*       om   = wave ? out_mem_ab : out_mem_l;

    const float2 m2 = ((const float2*)(mem  + (size_t)yb * D_))[lane];
    const float2 f2 = ((const float2*)(feat + (size_t)b  * D_))[lane];

    float px = m2.x * MOM_ + f2.x * (1.0f - MOM_);
    float py = m2.y * MOM_ + f2.y * (1.0f - MOM_);
    float ss = px * px + py * py;
    #pragma unroll
    for (int m = 32; m >= 1; m >>= 1) ss += __shfl_xor(ss, m);
    const float rn = 1.0f / sqrtf(ss);

    ((float2*)(om + (size_t)yb * D_))[lane] = make_float2(px * rn, py * rn);
}

extern "C" void kernel_launch(void* const* d_in, const int* in_sizes, int n_in,
                              void* d_out, int out_size, void* d_ws, size_t ws_size,
                              hipStream_t stream) {
    const float* l      = (const float*)d_in[0];
    const float* ab     = (const float*)d_in[1];
    const float* mem_l  = (const float*)d_in[2];
    const float* mem_ab = (const float*)d_in[3];
    const int*   y      = (const int*)d_in[4];
    const int*   idx    = (const int*)d_in[5];
    float* out = (float*)d_out;

    float* out_mem_l  = out + (size_t)(2 * BK_);
    float* out_mem_ab = out_mem_l + (size_t)NROW * D_;

    char* ws = (char*)d_ws;
    int*  counts  = (int*)(ws + WS_COUNTS);
    int*  partial = (int*)(ws + WS_PARTIAL);   // becomes scatter cursor
    int*  bsum    = (int*)(ws + WS_BSUM);
    int*  bscan   = (int*)(ws + WS_BSCAN);
    int2* entries = (int2*)(ws + WS_ENTRIES);

    hipMemsetAsync(counts, 0, (size_t)PADROWS * 4, stream);
    hist_kernel   <<<2048, 256, 0, stream>>>(idx, counts);
    scan1_kernel  <<<NCHUNK, 256, 0, stream>>>(counts, partial, bsum);
    scan2_kernel  <<<1, 256, 0, stream>>>(bsum, bscan);
    scatter_kernel<<<2048, 256, 0, stream>>>(idx, partial, bscan, entries);
    stream_kernel <<<NBLK, 256, 0, stream>>>(l, ab, mem_l, mem_ab, entries,
                                             out, out_mem_l, out_mem_ab);
    ema_update_kernel<<<B_, 128, 0, stream>>>(l, ab, mem_l, mem_ab, y,
                                              out_mem_l, out_mem_ab);
}

// Round 10
// 311.977 us; speedup vs baseline: 1.5090x; 1.5090x over previous
//
#include <hip/hip_runtime.h>
#include <math.h>

#define B_    64
#define KP1   16385                // K+1
#define D_    128
#define N_    500000
#define INV_T (1.0f / 0.07f)
#define MOM_  0.5f

#define NBLK   2048
#define NTHR   (NBLK * 256)        // 524288 threads
#define NGRP   (NBLK * 8)          // 16384 32-lane groups
#define BK_    (B_ * KP1)          // 1048640 items per bank (%4 == 0)
#define NQUAD  (BK_ / 4)           // 262160 paired quads (each covers both banks)
#define NE4B   (N_ * D_ / 4)       // 16,000,000 float4 per bank
#define NSTEP  16                  // NQUAD / NGRP
#define REMG   (NQUAD - NSTEP * NGRP)   // 16 leftover quads -> first 16 groups
#define CPITER 31                  // ceil(NE4B / NTHR); last iter partial

typedef float vfloat4 __attribute__((ext_vector_type(4)));

__device__ __forceinline__ float dot4(const float4 r, const float4 f) {
    return r.x * f.x + r.y * f.y + r.z * f.z + r.w * f.w;
}

// Paired score quad: items u0..u0+3 of BOTH banks (same idx rows).
// 8 independent 512B cooperative row bursts in flight per call; stores stay
// coalesced (two 16B bursts: out[u0..] and out[BK_+u0..]).
__device__ __forceinline__ void score_quad_pair(
        unsigned u0, int glane,
        const float* __restrict__ l, const float* __restrict__ ab,
        const float* __restrict__ mem_l, const float* __restrict__ mem_ab,
        const int* __restrict__ idx, float* __restrict__ out) {
    const unsigned b0 = u0 / KP1;              // magic-mul div
    const unsigned k0 = u0 - b0 * KP1;

    if (k0 <= (unsigned)(KP1 - 4)) {
        // fast path: all 4 items share b
        const int i0 = idx[u0],     i1 = idx[u0 + 1];
        const int i2 = idx[u0 + 2], i3 = idx[u0 + 3];

        const float4 a0 = ((const float4*)(mem_ab + (size_t)i0 * D_))[glane];
        const float4 a1 = ((const float4*)(mem_ab + (size_t)i1 * D_))[glane];
        const float4 a2 = ((const float4*)(mem_ab + (size_t)i2 * D_))[glane];
        const float4 a3 = ((const float4*)(mem_ab + (size_t)i3 * D_))[glane];
        const float4 m0 = ((const float4*)(mem_l  + (size_t)i0 * D_))[glane];
        const float4 m1 = ((const float4*)(mem_l  + (size_t)i1 * D_))[glane];
        const float4 m2 = ((const float4*)(mem_l  + (size_t)i2 * D_))[glane];
        const float4 m3 = ((const float4*)(mem_l  + (size_t)i3 * D_))[glane];

        const float4 fl = ((const float4*)(l  + (size_t)b0 * D_))[glane];
        const float4 fa = ((const float4*)(ab + (size_t)b0 * D_))[glane];

        float sl0 = dot4(a0, fl), sl1 = dot4(a1, fl);
        float sl2 = dot4(a2, fl), sl3 = dot4(a3, fl);
        float sa0 = dot4(m0, fa), sa1 = dot4(m1, fa);
        float sa2 = dot4(m2, fa), sa3 = dot4(m3, fa);

        #pragma unroll
        for (int m = 16; m >= 1; m >>= 1) {
            sl0 += __shfl_xor(sl0, m);  sl1 += __shfl_xor(sl1, m);
            sl2 += __shfl_xor(sl2, m);  sl3 += __shfl_xor(sl3, m);
            sa0 += __shfl_xor(sa0, m);  sa1 += __shfl_xor(sa1, m);
            sa2 += __shfl_xor(sa2, m);  sa3 += __shfl_xor(sa3, m);
        }
        const float vl = glane == 1 ? sl1 : glane == 2 ? sl2 : glane == 3 ? sl3 : sl0;
        const float va = glane == 1 ? sa1 : glane == 2 ? sa2 : glane == 3 ? sa3 : sa0;
        if (glane < 4) {
            __builtin_nontemporal_store(vl * INV_T, out + u0 + glane);
            __builtin_nontemporal_store(va * INV_T, out + BK_ + u0 + glane);
        }
    } else {
        // slow path: quad crosses a b boundary — per item
        #pragma unroll
        for (int i = 0; i < 4; ++i) {
            const unsigned u = u0 + i;
            const unsigned b = u / KP1;
            const int r = idx[u];
            const float4 a = ((const float4*)(mem_ab + (size_t)r * D_))[glane];
            const float4 m = ((const float4*)(mem_l  + (size_t)r * D_))[glane];
            const float4 fl = ((const float4*)(l  + (size_t)b * D_))[glane];
            const float4 fa = ((const float4*)(ab + (size_t)b * D_))[glane];
            float sl = dot4(a, fl), sa = dot4(m, fa);
            #pragma unroll
            for (int mm = 16; mm >= 1; mm >>= 1) {
                sl += __shfl_xor(sl, mm);
                sa += __shfl_xor(sa, mm);
            }
            if (glane == 0) {
                __builtin_nontemporal_store(sl * INV_T, out + u);
                __builtin_nontemporal_store(sa * INV_T, out + BK_ + u);
            }
        }
    }
}

__device__ __forceinline__ void copy_iter(const vfloat4* __restrict__ src,
                                          vfloat4* __restrict__ dst,
                                          int c, unsigned tid) {
    if (c < CPITER) {
        const size_t e = (size_t)c * NTHR + tid;
        if (e < (size_t)NE4B)
            __builtin_nontemporal_store(src[e], dst + e);
    }
}

// Uniform-mixed kernel: per j-step every thread does 2 copy iters per bank
// (streaming, NT stores) and every 32-lane group one PAIRED score quad
// (8 gather bursts in flight). Streaming fills BW while gathers stall.
__global__ __launch_bounds__(256)
void fused_kernel(const float* __restrict__ l,
                  const float* __restrict__ ab,
                  const float* __restrict__ mem_l,
                  const float* __restrict__ mem_ab,
                  const int* __restrict__ idx,
                  float* __restrict__ out,          // scores [2*BK_]
                  float* __restrict__ out_mem_l,
                  float* __restrict__ out_mem_ab) {
    const unsigned tid   = blockIdx.x * 256u + threadIdx.x;
    const int      glane = threadIdx.x & 31;
    const unsigned g     = (blockIdx.x << 3) + (threadIdx.x >> 5);

    const vfloat4* srcL = (const vfloat4*)mem_l;
    const vfloat4* srcA = (const vfloat4*)mem_ab;
    vfloat4* dstL = (vfloat4*)out_mem_l;
    vfloat4* dstA = (vfloat4*)out_mem_ab;

    for (int j = 0; j < NSTEP; ++j) {
        copy_iter(srcL, dstL, 2 * j,     tid);
        copy_iter(srcA, dstA, 2 * j,     tid);
        copy_iter(srcL, dstL, 2 * j + 1, tid);
        copy_iter(srcA, dstA, 2 * j + 1, tid);
        score_quad_pair(4u * (g + (unsigned)j * NGRP), glane,
                        l, ab, mem_l, mem_ab, idx, out);
    }
    if (g < REMG)
        score_quad_pair(4u * ((unsigned)NSTEP * NGRP + g), glane,
                        l, ab, mem_l, mem_ab, idx, out);
}

// EMA + L2-normalize the B updated rows; runs AFTER fused_kernel (stream
// order) so it overwrites the copied rows. Reads ORIGINAL banks from d_in.
__global__ __launch_bounds__(128)
void ema_update_kernel(const float* __restrict__ l,
                       const float* __restrict__ ab,
                       const float* __restrict__ mem_l,
                       const float* __restrict__ mem_ab,
                       const int* __restrict__ y,
                       float* __restrict__ out_mem_l,
                       float* __restrict__ out_mem_ab) {
    const int b    = blockIdx.x;
    const int wave = threadIdx.x >> 6;
    const int lane = threadIdx.x & 63;
    const int yb   = y[b];

    const float* mem  = wave ? mem_ab     : mem_l;
    const float* feat = wave ? ab         : l;
    float*       om   = wave ? out_mem_ab : out_mem_l;

    const float2 m2 = ((const float2*)(mem  + (size_t)yb * D_))[lane];
    const float2 f2 = ((const float2*)(feat + (size_t)b  * D_))[lane];

    float px = m2.x * MOM_ + f2.x * (1.0f - MOM_);
    float py = m2.y * MOM_ + f2.y * (1.0f - MOM_);
    float ss = px * px + py * py;
    #pragma unroll
    for (int m = 32; m >= 1; m >>= 1) ss += __shfl_xor(ss, m);
    const float rn = 1.0f / sqrtf(ss);

    ((float2*)(om + (size_t)yb * D_))[lane] = make_float2(px * rn, py * rn);
}

extern "C" void kernel_launch(void* const* d_in, const int* in_sizes, int n_in,
                              void* d_out, int out_size, void* d_ws, size_t ws_size,
                              hipStream_t stream) {
    const float* l      = (const float*)d_in[0];
    const float* ab     = (const float*)d_in[1];
    const float* mem_l  = (const float*)d_in[2];
    const float* mem_ab = (const float*)d_in[3];
    const int*   y      = (const int*)d_in[4];
    const int*   idx    = (const int*)d_in[5];
    float* out = (float*)d_out;

    float* out_mem_l  = out + (size_t)(2 * BK_);
    float* out_mem_ab = out_mem_l + (size_t)N_ * D_;

    fused_kernel<<<NBLK, 256, 0, stream>>>(l, ab, mem_l, mem_ab, idx,
                                           out, out_mem_l, out_mem_ab);
    ema_update_kernel<<<B_, 128, 0, stream>>>(l, ab, mem_l, mem_ab, y,
                                              out_mem_l, out_mem_ab);
}